// Round 9
// baseline (364.076 us; speedup 1.0000x reference)
//
#include <hip/hip_runtime.h>
#include <hip/hip_bf16.h>
#include <cstdint>

#define INCH 128
#define NHID 256
#define OUTCH 128
#define CAP 64   // bucket capacity; deg ~ Poisson(16), P(deg>64) ~ 1e-13

typedef unsigned short u16;
typedef unsigned long long u64;
typedef __attribute__((ext_vector_type(8))) short s8v;   // 8 bf16 (4 VGPRs)
typedef __attribute__((ext_vector_type(4))) float f4v;   // 4 fp32 acc

// ---------------- bf16 helpers ----------------
__device__ __forceinline__ u16 tob(float a) {             // RTN-even bf16
    unsigned u = __float_as_uint(a);
    return (u16)((u + 0x7fffu + ((u >> 16) & 1u)) >> 16);
}

__device__ __forceinline__ void bsplit(float a, u16& hi, u16& lo) {
    unsigned u = __float_as_uint(a);
    unsigned r = (u + 0x7fffu + ((u >> 16) & 1u)) >> 16;
    hi = (u16)r;
    float res = a - __uint_as_float(r << 16);
    lo = tob(res);
}

// ---------------- threefry2x32 (JAX-compatible) ----------------
__device__ __forceinline__ unsigned rotl32(unsigned x, int d) {
    return (x << d) | (x >> (32 - d));
}

__device__ __forceinline__ void threefry2x32(unsigned k0, unsigned k1,
                                             unsigned x0, unsigned x1,
                                             unsigned& o0, unsigned& o1) {
    unsigned ks2 = k0 ^ k1 ^ 0x1BD11BDAu;
#define TF_R(r) { x0 += x1; x1 = rotl32(x1, (r)); x1 ^= x0; }
    x0 += k0; x1 += k1;
    TF_R(13) TF_R(15) TF_R(26) TF_R(6)
    x0 += k1; x1 += ks2 + 1u;
    TF_R(17) TF_R(29) TF_R(16) TF_R(24)
    x0 += ks2; x1 += k0 + 2u;
    TF_R(13) TF_R(15) TF_R(26) TF_R(6)
    x0 += k0; x1 += k1 + 3u;
    TF_R(17) TF_R(29) TF_R(16) TF_R(24)
    x0 += k1; x1 += ks2 + 4u;
    TF_R(13) TF_R(15) TF_R(26) TF_R(6)
    x0 += ks2; x1 += k0 + 5u;
#undef TF_R
    o0 = x0; o1 = x1;
}

// ---------------- graph preprocessing: bucket CSR ----------------
__global__ void k_zero64(u64* packed, int N) {
    int i = blockIdx.x * blockDim.x + threadIdx.x;
    if (i < N) packed[i] = 0ull;
}

// ONE u64 atomic per edge: high32 = count (gives bucket pos via returned old),
// low32 = sum(w) in 8.24 fixed point (degree). Entry = {bf16(w) hi | src lo}.
__global__ void k_fill64(const int* __restrict__ src, const int* __restrict__ dst,
                         const float* __restrict__ w, u64* packed,
                         unsigned* __restrict__ buck, int E) {
    int e = blockIdx.x * blockDim.x + threadIdx.x;
    if (e < E) {
        int d = dst[e];
        float wv = w[e];
        u64 a = (1ull << 32) | (u64)__float2uint_rn(wv * 16777216.0f);
        u64 old = atomicAdd(&packed[d], a);
        unsigned pos = (unsigned)(old >> 32);
        if (pos < CAP)
            buck[(size_t)d * CAP + pos] = ((unsigned)tob(wv) << 16) | (unsigned)src[e];
    }
}

__global__ void k_dinv(const u64* __restrict__ packed, float* __restrict__ dinv, int N) {
    int i = blockIdx.x * blockDim.x + threadIdx.x;
    if (i < N) {
        float deg = 1.0f + (float)(unsigned)(packed[i] & 0xffffffffull) * (1.0f / 16777216.0f);
        dinv[i] = rsqrtf(deg);
    }
}

// val = dinv[src] * w * dinv[node], re-packed bf16 in place. 8 nodes x 32 lanes.
__global__ __launch_bounds__(256) void k_norm(unsigned* __restrict__ buck,
                                              const u64* __restrict__ packed,
                                              const float* __restrict__ dinv, int N) {
    int node = blockIdx.x * 8 + (threadIdx.x >> 5);
    int l = threadIdx.x & 31;
    if (node >= N) return;
    int c = min((int)(packed[node] >> 32), CAP);
    float dd = dinv[node];
    for (int p = l; p < c; p += 32) {
        unsigned u = buck[(size_t)node * CAP + p];
        unsigned s = u & 0xffffu;
        float wv = __uint_as_float(u & 0xffff0000u);
        float v = dinv[s] * wv * dd;
        buck[(size_t)node * CAP + p] = ((unsigned)tob(v) << 16) | s;
    }
}

// ---------------- fused prep: tobf16(x) + mask + W1 split + W2 split --------
__global__ __launch_bounds__(256) void k_prep(const float4* __restrict__ x,
                                              uint4* __restrict__ xb,
                                              unsigned* __restrict__ mask,
                                              const float* __restrict__ W1,
                                              u16* __restrict__ w1h, u16* __restrict__ w1l,
                                              const float* __restrict__ W2,
                                              u16* __restrict__ w2h, u16* __restrict__ w2l,
                                              int n8, int nwords) {
    int i = blockIdx.x * 256 + threadIdx.x;
    if (i < n8) {   // x -> bf16 plane, 8 elems
        float4 a = x[i * 2], b = x[i * 2 + 1];
        uint4 o;
        o.x = (unsigned)tob(a.x) | ((unsigned)tob(a.y) << 16);
        o.y = (unsigned)tob(a.z) | ((unsigned)tob(a.w) << 16);
        o.z = (unsigned)tob(b.x) | ((unsigned)tob(b.y) << 16);
        o.w = (unsigned)tob(b.z) | ((unsigned)tob(b.w) << 16);
        xb[i] = o;
    }
    if (i < nwords) {   // dropout mask word
        unsigned base = (unsigned)i * 32u;
        unsigned m = 0;
#pragma unroll
        for (int b = 0; b < 32; ++b) {
            unsigned o0, o1;
            threefry2x32(0u, 42u, 0u, base + (unsigned)b, o0, o1);
            m |= ((((o0 ^ o1) >> 31) ^ 1u) & 1u) << b;
        }
        mask[i] = m;
    }
    if (i < INCH * NHID) {   // W1[K][N] -> [N][K] hi/lo
        int k = i / NHID, n = i % NHID;
        u16 hi, lo;
        bsplit(W1[i], hi, lo);
        w1h[(size_t)n * INCH + k] = hi;
        w1l[(size_t)n * INCH + k] = lo;
    }
    if (i < NHID * OUTCH) {  // W2
        int k = i / OUTCH, n = i % OUTCH;
        u16 hi, lo;
        bsplit(W2[i], hi, lo);
        w2h[(size_t)n * NHID + k] = hi;
        w2l[(size_t)n * NHID + k] = lo;
    }
}

// ---------------- MFMA split-bf16 GEMM (BK=32, small LDS) ----------------
// C[M,Ntot] = A[M,K] @ B^T[Ntot,K]; A/B as bf16 hi/lo planes.
// MODE 0: C = maskbit ? 2*relu(C+bias) : 0 -> Ch/Cl planes.
// MODE 1: Cb = bf16(C); Sp = dinv[row]^2*C + bias[col] (fp32).
template <int BM, int BN, int MODE>
__global__ __launch_bounds__(256) void gemm_mfma(
    const u16* __restrict__ Ah, const u16* __restrict__ Al,
    const u16* __restrict__ Bh, const u16* __restrict__ Bl,
    const float* __restrict__ bias, const unsigned* __restrict__ mask,
    const float* __restrict__ dinv,
    u16* __restrict__ Ch, u16* __restrict__ Cl,
    u16* __restrict__ Cb, float* __restrict__ Sp,
    int M, int Ntot, int K) {
    constexpr int WN = BN / 2;
    constexpr int MFRAG = BM / 32;
    constexpr int NFRAG = WN / 16;
    __shared__ u16 Alh[BM][40], All[BM][40];
    __shared__ u16 Blh[BN][40], Bll[BN][40];

    const int tid = threadIdx.x;
    const int lane = tid & 63;
    const int w = tid >> 6;
    const int wm = (w >> 1) * (BM / 2);
    const int wn = (w & 1) * WN;
    const int l15 = lane & 15;
    const int kh = lane >> 4;            // 0..3
    const int row0 = blockIdx.y * BM;
    const int col0 = blockIdx.x * BN;

    f4v acc[MFRAG][NFRAG];
#pragma unroll
    for (int f = 0; f < MFRAG; ++f)
#pragma unroll
        for (int g = 0; g < NFRAG; ++g) acc[f][g] = (f4v){0.f, 0.f, 0.f, 0.f};

    for (int k0 = 0; k0 < K; k0 += 32) {
#pragma unroll
        for (int c = tid; c < BM * 4; c += 256) {
            int m = c >> 2, ko = (c & 3) * 8;
            int gm = row0 + m;
            uint4 vh = make_uint4(0, 0, 0, 0), vl = make_uint4(0, 0, 0, 0);
            if (gm < M) {
                size_t gi = (size_t)gm * K + k0 + ko;
                vh = *reinterpret_cast<const uint4*>(&Ah[gi]);
                vl = *reinterpret_cast<const uint4*>(&Al[gi]);
            }
            *reinterpret_cast<uint4*>(&Alh[m][ko]) = vh;
            *reinterpret_cast<uint4*>(&All[m][ko]) = vl;
        }
#pragma unroll
        for (int c = tid; c < BN * 4; c += 256) {
            int n = c >> 2, ko = (c & 3) * 8;
            size_t gi = (size_t)(col0 + n) * K + k0 + ko;
            *reinterpret_cast<uint4*>(&Blh[n][ko]) = *reinterpret_cast<const uint4*>(&Bh[gi]);
            *reinterpret_cast<uint4*>(&Bll[n][ko]) = *reinterpret_cast<const uint4*>(&Bl[gi]);
        }
        __syncthreads();

        s8v afh[MFRAG], afl[MFRAG], bfh[NFRAG], bfl[NFRAG];
#pragma unroll
        for (int f = 0; f < MFRAG; ++f) {
            afh[f] = *reinterpret_cast<const s8v*>(&Alh[wm + f * 16 + l15][kh * 8]);
            afl[f] = *reinterpret_cast<const s8v*>(&All[wm + f * 16 + l15][kh * 8]);
        }
#pragma unroll
        for (int g = 0; g < NFRAG; ++g) {
            bfh[g] = *reinterpret_cast<const s8v*>(&Blh[wn + g * 16 + l15][kh * 8]);
            bfl[g] = *reinterpret_cast<const s8v*>(&Bll[wn + g * 16 + l15][kh * 8]);
        }
#pragma unroll
        for (int f = 0; f < MFRAG; ++f)
#pragma unroll
            for (int g = 0; g < NFRAG; ++g) {
                acc[f][g] = __builtin_amdgcn_mfma_f32_16x16x32_bf16(afl[f], bfh[g], acc[f][g], 0, 0, 0);
                acc[f][g] = __builtin_amdgcn_mfma_f32_16x16x32_bf16(afh[f], bfl[g], acc[f][g], 0, 0, 0);
                acc[f][g] = __builtin_amdgcn_mfma_f32_16x16x32_bf16(afh[f], bfh[g], acc[f][g], 0, 0, 0);
            }
        __syncthreads();
    }

    // epilogue
#pragma unroll
    for (int f = 0; f < MFRAG; ++f) {
#pragma unroll
        for (int g = 0; g < NFRAG; ++g) {
#pragma unroll
            for (int r = 0; r < 4; ++r) {
                int gr = row0 + wm + f * 16 + kh * 4 + r;
                if (gr >= M) continue;
                int gc = col0 + wn + g * 16 + l15;
                float v = acc[f][g][r];
                if (MODE == 0) {
                    v = fmaxf(v + bias[gc], 0.f);
                    unsigned j = (unsigned)gr * (unsigned)Ntot + (unsigned)gc;
                    unsigned keep = (mask[j >> 5] >> (j & 31u)) & 1u;
                    v = keep ? v * 2.f : 0.f;
                    u16 hi, lo;
                    bsplit(v, hi, lo);
                    Ch[(size_t)gr * Ntot + gc] = hi;
                    Cl[(size_t)gr * Ntot + gc] = lo;
                } else {
                    float d = dinv[gr];
                    Cb[(size_t)gr * Ntot + gc] = tob(v);
                    Sp[(size_t)gr * Ntot + gc] = fmaf(v, d * d, bias[gc]);
                }
            }
        }
    }
}

// ------- quartered bucket gather: 32-feature slice (3.2MB -> L2-resident) -----
// 64 nodes/block, 4 lanes/node x 16B. Launched 4x sequentially (q = 0..3).
// SPLIT (layer 1): acc = selfs*dinv^2 + sum val*gb[src]; out bf16 hi/lo planes.
// !SPLIT (layer 2): acc = selfs (pre-scaled+bias) + sum val*gb[src]; fp32 out.
template <bool SPLIT>
__global__ __launch_bounds__(256) void k_agg_q(const uint4* __restrict__ gb,
                                               const float4* __restrict__ selfs,
                                               const float* __restrict__ dinv,
                                               const u64* __restrict__ packed,
                                               const unsigned* __restrict__ buck,
                                               uint4* __restrict__ outh,
                                               uint4* __restrict__ outl,
                                               float4* __restrict__ outf,
                                               int N, int q) {
    int node = blockIdx.x * 64 + (threadIdx.x >> 2);
    int l = threadIdx.x & 3;
    if (node >= N) return;
    const int q4 = q * 4 + l;        // uint4 index within 16-uint4 row
    const int q8 = q * 8 + l * 2;    // float4 index within 32-float4 row
    float4 s0 = selfs[(size_t)node * 32 + q8];
    float4 s1 = selfs[(size_t)node * 32 + q8 + 1];
    float a0, a1, a2, a3, a4, a5, a6, a7;
    if (SPLIT) {
        float d = dinv[node], sc = d * d;
        a0 = s0.x * sc; a1 = s0.y * sc; a2 = s0.z * sc; a3 = s0.w * sc;
        a4 = s1.x * sc; a5 = s1.y * sc; a6 = s1.z * sc; a7 = s1.w * sc;
    } else {
        a0 = s0.x; a1 = s0.y; a2 = s0.z; a3 = s0.w;
        a4 = s1.x; a5 = s1.y; a6 = s1.z; a7 = s1.w;
    }
#define ACCB(gv, ev) { float v = __uint_as_float((ev) & 0xffff0000u); \
    a0 = fmaf(__uint_as_float((gv).x << 16), v, a0); \
    a1 = fmaf(__uint_as_float((gv).x & 0xffff0000u), v, a1); \
    a2 = fmaf(__uint_as_float((gv).y << 16), v, a2); \
    a3 = fmaf(__uint_as_float((gv).y & 0xffff0000u), v, a3); \
    a4 = fmaf(__uint_as_float((gv).z << 16), v, a4); \
    a5 = fmaf(__uint_as_float((gv).z & 0xffff0000u), v, a5); \
    a6 = fmaf(__uint_as_float((gv).w << 16), v, a6); \
    a7 = fmaf(__uint_as_float((gv).w & 0xffff0000u), v, a7); }
    int c = min((int)(packed[node] >> 32), CAP);
    const unsigned* row = buck + (size_t)node * CAP;
    int p = 0;
    for (; p + 8 <= c; p += 8) {
        unsigned e0 = row[p + 0], e1 = row[p + 1], e2 = row[p + 2], e3 = row[p + 3];
        unsigned e4 = row[p + 4], e5 = row[p + 5], e6 = row[p + 6], e7 = row[p + 7];
        uint4 g0 = gb[(size_t)(e0 & 0xffffu) * 16 + q4];
        uint4 g1 = gb[(size_t)(e1 & 0xffffu) * 16 + q4];
        uint4 g2 = gb[(size_t)(e2 & 0xffffu) * 16 + q4];
        uint4 g3 = gb[(size_t)(e3 & 0xffffu) * 16 + q4];
        uint4 g4 = gb[(size_t)(e4 & 0xffffu) * 16 + q4];
        uint4 g5 = gb[(size_t)(e5 & 0xffffu) * 16 + q4];
        uint4 g6 = gb[(size_t)(e6 & 0xffffu) * 16 + q4];
        uint4 g7 = gb[(size_t)(e7 & 0xffffu) * 16 + q4];
        ACCB(g0, e0) ACCB(g1, e1) ACCB(g2, e2) ACCB(g3, e3)
        ACCB(g4, e4) ACCB(g5, e5) ACCB(g6, e6) ACCB(g7, e7)
    }
    for (; p < c; ++p) {
        unsigned e = row[p];
        uint4 g = gb[(size_t)(e & 0xffffu) * 16 + q4];
        ACCB(g, e)
    }
#undef ACCB
    if (SPLIT) {
        u16 h[8], lo[8];
        bsplit(a0, h[0], lo[0]); bsplit(a1, h[1], lo[1]);
        bsplit(a2, h[2], lo[2]); bsplit(a3, h[3], lo[3]);
        bsplit(a4, h[4], lo[4]); bsplit(a5, h[5], lo[5]);
        bsplit(a6, h[6], lo[6]); bsplit(a7, h[7], lo[7]);
        uint4 oh, ol;
        oh.x = (unsigned)h[0] | ((unsigned)h[1] << 16);
        oh.y = (unsigned)h[2] | ((unsigned)h[3] << 16);
        oh.z = (unsigned)h[4] | ((unsigned)h[5] << 16);
        oh.w = (unsigned)h[6] | ((unsigned)h[7] << 16);
        ol.x = (unsigned)lo[0] | ((unsigned)lo[1] << 16);
        ol.y = (unsigned)lo[2] | ((unsigned)lo[3] << 16);
        ol.z = (unsigned)lo[4] | ((unsigned)lo[5] << 16);
        ol.w = (unsigned)lo[6] | ((unsigned)lo[7] << 16);
        outh[(size_t)node * 16 + q4] = oh;
        outl[(size_t)node * 16 + q4] = ol;
    } else {
        outf[(size_t)node * 32 + q8]     = make_float4(a0, a1, a2, a3);
        outf[(size_t)node * 32 + q8 + 1] = make_float4(a4, a5, a6, a7);
    }
}

// ---------------- launch ----------------
extern "C" void kernel_launch(void* const* d_in, const int* in_sizes, int n_in,
                              void* d_out, int out_size, void* d_ws, size_t ws_size,
                              hipStream_t stream) {
    (void)n_in; (void)out_size; (void)ws_size;
    const float* x  = (const float*)d_in[0];
    const int*   ei = (const int*)d_in[1];
    const float* w  = (const float*)d_in[2];
    const float* W1 = (const float*)d_in[3];
    const float* b1 = (const float*)d_in[4];
    const float* W2 = (const float*)d_in[5];
    const float* b2 = (const float*)d_in[6];
    float* out = (float*)d_out;

    int N = in_sizes[0] / INCH;  // 50000
    int E = in_sizes[1] / 2;     // 800000
    const int* src = ei;
    const int* dst = ei + E;

    char* ws = (char*)d_ws;
    size_t off = 0;
    auto alloc = [&](size_t bytes) -> char* {
        size_t p = (off + 255) & ~(size_t)255;
        off = p + bytes;
        return ws + p;
    };
    u64*      packed = (u64*)     alloc((size_t)N * 8);
    float*    dinv   = (float*)   alloc((size_t)N * 4);
    unsigned* buck   = (unsigned*)alloc((size_t)N * CAP * 4);    // 12.8 MB
    unsigned* mask   = (unsigned*)alloc((size_t)N * NHID / 8);
    u16*      xb     = (u16*)     alloc((size_t)N * INCH * 2);   // bf16 x, later g2b
    u16*      axh    = (u16*)     alloc((size_t)N * INCH * 2);
    u16*      axl    = (u16*)     alloc((size_t)N * INCH * 2);
    u16*      hdh    = (u16*)     alloc((size_t)N * NHID * 2);
    u16*      hdl    = (u16*)     alloc((size_t)N * NHID * 2);
    u16*      w1h    = (u16*)     alloc((size_t)INCH * NHID * 2);
    u16*      w1l    = (u16*)     alloc((size_t)INCH * NHID * 2);
    u16*      w2h    = (u16*)     alloc((size_t)NHID * OUTCH * 2);
    u16*      w2l    = (u16*)     alloc((size_t)NHID * OUTCH * 2);
    // aliases (stream-ordered safe):
    u16*      g2b    = xb;               // xb dead after agg1
    float*    sp     = (float*)axh;      // axh+axl contiguous 25.6 MB, dead after gemm1

    int nb = (N + 255) / 256;
    int eb = (E + 255) / 256;
    int n8 = N * INCH / 8;
    int nwords = N * NHID / 32;
    int hb = (N + 7) / 8;     // k_norm: 8 nodes x 32 lanes
    int qb = (N + 63) / 64;   // quartered aggs: 64 nodes x 4 lanes

    k_zero64<<<nb, 256, 0, stream>>>(packed, N);
    k_fill64<<<eb, 256, 0, stream>>>(src, dst, w, packed, buck, E);
    k_dinv<<<nb, 256, 0, stream>>>(packed, dinv, N);
    k_norm<<<hb, 256, 0, stream>>>(buck, packed, dinv, N);
    k_prep<<<(n8 + 255) / 256, 256, 0, stream>>>((const float4*)x, (uint4*)xb, mask,
                                                 W1, w1h, w1l, W2, w2h, w2l, n8, nwords);

    // layer 1: ax = A@x (quartered bf16 gather + fp32 self) -> split planes
    for (int q = 0; q < 4; ++q)
        k_agg_q<true><<<qb, 256, 0, stream>>>((const uint4*)xb, (const float4*)x, dinv,
                                              packed, buck, (uint4*)axh, (uint4*)axl,
                                              nullptr, N, q);
    // hd = dropout(relu(ax @ W1 + b1)) -> split planes
    dim3 gg1(NHID / 128, (N + 63) / 64);
    gemm_mfma<64, 128, 0><<<gg1, 256, 0, stream>>>(axh, axl, w1h, w1l, b1, mask, nullptr,
                                                   hdh, hdl, nullptr, nullptr,
                                                   N, NHID, INCH);
    // g2 = hd @ W2 -> bf16 gather plane + fused self-part sp = dinv^2*g2 + b2
    dim3 gg2(OUTCH / 64, (N + 63) / 64);
    gemm_mfma<64, 64, 1><<<gg2, 256, 0, stream>>>(hdh, hdl, w2h, w2l, b2, nullptr, dinv,
                                                  nullptr, nullptr, g2b, sp,
                                                  N, OUTCH, NHID);
    // out = sp + sum val * g2b[src] (quartered)
    for (int q = 0; q < 4; ++q)
        k_agg_q<false><<<qb, 256, 0, stream>>>((const uint4*)g2b, (const float4*)sp, nullptr,
                                               packed, buck, nullptr, nullptr,
                                               (float4*)out, N, q);
}

// Round 10
// 332.300 us; speedup vs baseline: 1.0956x; 1.0956x over previous
//
#include <hip/hip_runtime.h>
#include <hip/hip_bf16.h>
#include <cstdint>

#define INCH 128
#define NHID 256
#define OUTCH 128
#define CAP 64   // bucket capacity; deg ~ Poisson(16), P(deg>64) ~ 1e-13

typedef unsigned short u16;
typedef unsigned long long u64;
typedef __attribute__((ext_vector_type(8))) short s8v;   // 8 bf16 (4 VGPRs)
typedef __attribute__((ext_vector_type(4))) float f4v;   // 4 fp32 acc

// ---------------- bf16 helpers ----------------
__device__ __forceinline__ u16 tob(float a) {             // RTN-even bf16
    unsigned u = __float_as_uint(a);
    return (u16)((u + 0x7fffu + ((u >> 16) & 1u)) >> 16);
}

__device__ __forceinline__ void bsplit(float a, u16& hi, u16& lo) {
    unsigned u = __float_as_uint(a);
    unsigned r = (u + 0x7fffu + ((u >> 16) & 1u)) >> 16;
    hi = (u16)r;
    float res = a - __uint_as_float(r << 16);
    lo = tob(res);
}

// ---------------- threefry2x32 (JAX-compatible) ----------------
__device__ __forceinline__ unsigned rotl32(unsigned x, int d) {
    return (x << d) | (x >> (32 - d));
}

__device__ __forceinline__ void threefry2x32(unsigned k0, unsigned k1,
                                             unsigned x0, unsigned x1,
                                             unsigned& o0, unsigned& o1) {
    unsigned ks2 = k0 ^ k1 ^ 0x1BD11BDAu;
#define TF_R(r) { x0 += x1; x1 = rotl32(x1, (r)); x1 ^= x0; }
    x0 += k0; x1 += k1;
    TF_R(13) TF_R(15) TF_R(26) TF_R(6)
    x0 += k1; x1 += ks2 + 1u;
    TF_R(17) TF_R(29) TF_R(16) TF_R(24)
    x0 += ks2; x1 += k0 + 2u;
    TF_R(13) TF_R(15) TF_R(26) TF_R(6)
    x0 += k0; x1 += k1 + 3u;
    TF_R(17) TF_R(29) TF_R(16) TF_R(24)
    x0 += k1; x1 += ks2 + 4u;
    TF_R(13) TF_R(15) TF_R(26) TF_R(6)
    x0 += ks2; x1 += k0 + 5u;
#undef TF_R
    o0 = x0; o1 = x1;
}

// ---------------- graph preprocessing: bucket CSR ----------------
__global__ void k_zero64(u64* packed, int N) {
    int i = blockIdx.x * blockDim.x + threadIdx.x;
    if (i < N) packed[i] = 0ull;
}

// ONE u64 atomic per edge: high32 = count (gives bucket pos via returned old),
// low32 = sum(w) in 8.24 fixed point (degree). Entry = {bf16(w) hi | src lo}.
__global__ void k_fill64(const int* __restrict__ src, const int* __restrict__ dst,
                         const float* __restrict__ w, u64* packed,
                         unsigned* __restrict__ buck, int E) {
    int e = blockIdx.x * blockDim.x + threadIdx.x;
    if (e < E) {
        int d = dst[e];
        float wv = w[e];
        u64 a = (1ull << 32) | (u64)__float2uint_rn(wv * 16777216.0f);
        u64 old = atomicAdd(&packed[d], a);
        unsigned pos = (unsigned)(old >> 32);
        if (pos < CAP)
            buck[(size_t)d * CAP + pos] = ((unsigned)tob(wv) << 16) | (unsigned)src[e];
    }
}

__global__ void k_dinv(const u64* __restrict__ packed, float* __restrict__ dinv, int N) {
    int i = blockIdx.x * blockDim.x + threadIdx.x;
    if (i < N) {
        float deg = 1.0f + (float)(unsigned)(packed[i] & 0xffffffffull) * (1.0f / 16777216.0f);
        dinv[i] = rsqrtf(deg);
    }
}

// val = dinv[src] * w * dinv[node], re-packed bf16 in place. 8 nodes x 32 lanes.
__global__ __launch_bounds__(256) void k_norm(unsigned* __restrict__ buck,
                                              const u64* __restrict__ packed,
                                              const float* __restrict__ dinv, int N) {
    int node = blockIdx.x * 8 + (threadIdx.x >> 5);
    int l = threadIdx.x & 31;
    if (node >= N) return;
    int c = min((int)(packed[node] >> 32), CAP);
    float dd = dinv[node];
    for (int p = l; p < c; p += 32) {
        unsigned u = buck[(size_t)node * CAP + p];
        unsigned s = u & 0xffffu;
        float wv = __uint_as_float(u & 0xffff0000u);
        float v = dinv[s] * wv * dd;
        buck[(size_t)node * CAP + p] = ((unsigned)tob(v) << 16) | s;
    }
}

// ---------------- fused prep: tobf16(x) + mask + W1 split + W2 split --------
__global__ __launch_bounds__(256) void k_prep(const float4* __restrict__ x,
                                              uint4* __restrict__ xb,
                                              unsigned* __restrict__ mask,
                                              const float* __restrict__ W1,
                                              u16* __restrict__ w1h, u16* __restrict__ w1l,
                                              const float* __restrict__ W2,
                                              u16* __restrict__ w2h, u16* __restrict__ w2l,
                                              int n8, int nwords) {
    int i = blockIdx.x * 256 + threadIdx.x;
    if (i < n8) {   // x -> bf16 plane, 8 elems
        float4 a = x[i * 2], b = x[i * 2 + 1];
        uint4 o;
        o.x = (unsigned)tob(a.x) | ((unsigned)tob(a.y) << 16);
        o.y = (unsigned)tob(a.z) | ((unsigned)tob(a.w) << 16);
        o.z = (unsigned)tob(b.x) | ((unsigned)tob(b.y) << 16);
        o.w = (unsigned)tob(b.z) | ((unsigned)tob(b.w) << 16);
        xb[i] = o;
    }
    if (i < nwords) {   // dropout mask word
        unsigned base = (unsigned)i * 32u;
        unsigned m = 0;
#pragma unroll
        for (int b = 0; b < 32; ++b) {
            unsigned o0, o1;
            threefry2x32(0u, 42u, 0u, base + (unsigned)b, o0, o1);
            m |= ((((o0 ^ o1) >> 31) ^ 1u) & 1u) << b;
        }
        mask[i] = m;
    }
    if (i < INCH * NHID) {   // W1[K][N] -> [N][K] hi/lo
        int k = i / NHID, n = i % NHID;
        u16 hi, lo;
        bsplit(W1[i], hi, lo);
        w1h[(size_t)n * INCH + k] = hi;
        w1l[(size_t)n * INCH + k] = lo;
    }
    if (i < NHID * OUTCH) {  // W2
        int k = i / OUTCH, n = i % OUTCH;
        u16 hi, lo;
        bsplit(W2[i], hi, lo);
        w2h[(size_t)n * NHID + k] = hi;
        w2l[(size_t)n * NHID + k] = lo;
    }
}

// ------- MFMA split-bf16 GEMM, BK=32, register-prefetch double-buffer -------
// C[M,Ntot] = A[M,K] @ B^T[Ntot,K]; A/B as bf16 hi/lo planes.
// MODE 0: C = maskbit ? 2*relu(C+bias) : 0 -> Ch/Cl planes.
// MODE 1: Cb = bf16(C); Sp = dinv[row]^2*C + bias[col] (fp32).
template <int BM, int BN, int MODE>
__global__ __launch_bounds__(256) void gemm_mfma(
    const u16* __restrict__ Ah, const u16* __restrict__ Al,
    const u16* __restrict__ Bh, const u16* __restrict__ Bl,
    const float* __restrict__ bias, const unsigned* __restrict__ mask,
    const float* __restrict__ dinv,
    u16* __restrict__ Ch, u16* __restrict__ Cl,
    u16* __restrict__ Cb, float* __restrict__ Sp,
    int M, int Ntot, int K) {
    constexpr int WN = BN / 2;
    constexpr int MFRAG = BM / 32;
    constexpr int NFRAG = WN / 16;
    constexpr int AV = BM * 4 / 256;   // uint4/thread/plane for A tile
    constexpr int BV = BN * 4 / 256;   // uint4/thread/plane for B tile
    __shared__ u16 Alh[BM][40], All[BM][40];
    __shared__ u16 Blh[BN][40], Bll[BN][40];

    const int tid = threadIdx.x;
    const int lane = tid & 63;
    const int w = tid >> 6;
    const int wm = (w >> 1) * (BM / 2);
    const int wn = (w & 1) * WN;
    const int l15 = lane & 15;
    const int kh = lane >> 4;            // 0..3
    const int row0 = blockIdx.y * BM;
    const int col0 = blockIdx.x * BN;

    f4v acc[MFRAG][NFRAG];
#pragma unroll
    for (int f = 0; f < MFRAG; ++f)
#pragma unroll
        for (int g = 0; g < NFRAG; ++g) acc[f][g] = (f4v){0.f, 0.f, 0.f, 0.f};

    uint4 pah[AV], pal[AV], pbh[BV], pbl[BV];

    auto loadg = [&](int k0) {
#pragma unroll
        for (int v = 0; v < AV; ++v) {
            int c = tid + v * 256;
            int m = c >> 2, ko = (c & 3) * 8;
            int gm = row0 + m;
            pah[v] = make_uint4(0, 0, 0, 0);
            pal[v] = make_uint4(0, 0, 0, 0);
            if (gm < M) {
                size_t gi = (size_t)gm * K + k0 + ko;
                pah[v] = *reinterpret_cast<const uint4*>(&Ah[gi]);
                pal[v] = *reinterpret_cast<const uint4*>(&Al[gi]);
            }
        }
#pragma unroll
        for (int v = 0; v < BV; ++v) {
            int c = tid + v * 256;
            int n = c >> 2, ko = (c & 3) * 8;
            size_t gi = (size_t)(col0 + n) * K + k0 + ko;
            pbh[v] = *reinterpret_cast<const uint4*>(&Bh[gi]);
            pbl[v] = *reinterpret_cast<const uint4*>(&Bl[gi]);
        }
    };
    auto store_lds = [&]() {
#pragma unroll
        for (int v = 0; v < AV; ++v) {
            int c = tid + v * 256;
            int m = c >> 2, ko = (c & 3) * 8;
            *reinterpret_cast<uint4*>(&Alh[m][ko]) = pah[v];
            *reinterpret_cast<uint4*>(&All[m][ko]) = pal[v];
        }
#pragma unroll
        for (int v = 0; v < BV; ++v) {
            int c = tid + v * 256;
            int n = c >> 2, ko = (c & 3) * 8;
            *reinterpret_cast<uint4*>(&Blh[n][ko]) = pbh[v];
            *reinterpret_cast<uint4*>(&Bll[n][ko]) = pbl[v];
        }
    };
    auto compute = [&]() {
        s8v afh[MFRAG], afl[MFRAG], bfh[NFRAG], bfl[NFRAG];
#pragma unroll
        for (int f = 0; f < MFRAG; ++f) {
            afh[f] = *reinterpret_cast<const s8v*>(&Alh[wm + f * 16 + l15][kh * 8]);
            afl[f] = *reinterpret_cast<const s8v*>(&All[wm + f * 16 + l15][kh * 8]);
        }
#pragma unroll
        for (int g = 0; g < NFRAG; ++g) {
            bfh[g] = *reinterpret_cast<const s8v*>(&Blh[wn + g * 16 + l15][kh * 8]);
            bfl[g] = *reinterpret_cast<const s8v*>(&Bll[wn + g * 16 + l15][kh * 8]);
        }
#pragma unroll
        for (int f = 0; f < MFRAG; ++f)
#pragma unroll
            for (int g = 0; g < NFRAG; ++g) {
                acc[f][g] = __builtin_amdgcn_mfma_f32_16x16x32_bf16(afl[f], bfh[g], acc[f][g], 0, 0, 0);
                acc[f][g] = __builtin_amdgcn_mfma_f32_16x16x32_bf16(afh[f], bfl[g], acc[f][g], 0, 0, 0);
                acc[f][g] = __builtin_amdgcn_mfma_f32_16x16x32_bf16(afh[f], bfh[g], acc[f][g], 0, 0, 0);
            }
    };

    // prologue
    loadg(0);
    store_lds();
    __syncthreads();
    // main loop: prefetch next K-chunk into regs while computing current
    for (int k0 = 32; k0 < K; k0 += 32) {
        loadg(k0);
        compute();
        __syncthreads();
        store_lds();
        __syncthreads();
    }
    compute();  // last chunk

    // epilogue
#pragma unroll
    for (int f = 0; f < MFRAG; ++f) {
#pragma unroll
        for (int g = 0; g < NFRAG; ++g) {
#pragma unroll
            for (int r = 0; r < 4; ++r) {
                int gr = row0 + wm + f * 16 + kh * 4 + r;
                if (gr >= M) continue;
                int gc = col0 + wn + g * 16 + l15;
                float v = acc[f][g][r];
                if (MODE == 0) {
                    v = fmaxf(v + bias[gc], 0.f);
                    unsigned j = (unsigned)gr * (unsigned)Ntot + (unsigned)gc;
                    unsigned keep = (mask[j >> 5] >> (j & 31u)) & 1u;
                    v = keep ? v * 2.f : 0.f;
                    u16 hi, lo;
                    bsplit(v, hi, lo);
                    Ch[(size_t)gr * Ntot + gc] = hi;
                    Cl[(size_t)gr * Ntot + gc] = lo;
                } else {
                    float d = dinv[gr];
                    Cb[(size_t)gr * Ntot + gc] = tob(v);
                    Sp[(size_t)gr * Ntot + gc] = fmaf(v, d * d, bias[gc]);
                }
            }
        }
    }
}

// ------------- bucket gather aggregation, bf16 table, 16 lanes x 16B --------
// SPLIT (layer 1): acc = selfs[n]*dinv[n]^2 + sum val*gb[col]; out hi/lo planes.
// !SPLIT (layer 2): acc = selfs[n] (pre-scaled+bias) + sum val*gb[col]; fp32 out.
template <bool SPLIT>
__global__ __launch_bounds__(256) void k_agg_b(const uint4* __restrict__ gb,
                                               const float4* __restrict__ selfs,
                                               const float* __restrict__ dinv,
                                               const u64* __restrict__ packed,
                                               const unsigned* __restrict__ buck,
                                               uint4* __restrict__ outh,
                                               uint4* __restrict__ outl,
                                               float4* __restrict__ outf, int N) {
    int node = blockIdx.x * 16 + (threadIdx.x >> 4);
    int l = threadIdx.x & 15;
    if (node >= N) return;
    float4 s0 = selfs[(size_t)node * 32 + l * 2];
    float4 s1 = selfs[(size_t)node * 32 + l * 2 + 1];
    float a0, a1, a2, a3, a4, a5, a6, a7;
    if (SPLIT) {
        float d = dinv[node], sc = d * d;
        a0 = s0.x * sc; a1 = s0.y * sc; a2 = s0.z * sc; a3 = s0.w * sc;
        a4 = s1.x * sc; a5 = s1.y * sc; a6 = s1.z * sc; a7 = s1.w * sc;
    } else {
        a0 = s0.x; a1 = s0.y; a2 = s0.z; a3 = s0.w;
        a4 = s1.x; a5 = s1.y; a6 = s1.z; a7 = s1.w;
    }
#define ACCB(gv, ev) { float v = __uint_as_float((ev) & 0xffff0000u); \
    a0 = fmaf(__uint_as_float((gv).x << 16), v, a0); \
    a1 = fmaf(__uint_as_float((gv).x & 0xffff0000u), v, a1); \
    a2 = fmaf(__uint_as_float((gv).y << 16), v, a2); \
    a3 = fmaf(__uint_as_float((gv).y & 0xffff0000u), v, a3); \
    a4 = fmaf(__uint_as_float((gv).z << 16), v, a4); \
    a5 = fmaf(__uint_as_float((gv).z & 0xffff0000u), v, a5); \
    a6 = fmaf(__uint_as_float((gv).w << 16), v, a6); \
    a7 = fmaf(__uint_as_float((gv).w & 0xffff0000u), v, a7); }
    int c = min((int)(packed[node] >> 32), CAP);
    const unsigned* row = buck + (size_t)node * CAP;
    int p = 0;
    for (; p + 8 <= c; p += 8) {
        unsigned e0 = row[p + 0], e1 = row[p + 1], e2 = row[p + 2], e3 = row[p + 3];
        unsigned e4 = row[p + 4], e5 = row[p + 5], e6 = row[p + 6], e7 = row[p + 7];
        uint4 g0 = gb[(size_t)(e0 & 0xffffu) * 16 + l];
        uint4 g1 = gb[(size_t)(e1 & 0xffffu) * 16 + l];
        uint4 g2 = gb[(size_t)(e2 & 0xffffu) * 16 + l];
        uint4 g3 = gb[(size_t)(e3 & 0xffffu) * 16 + l];
        uint4 g4 = gb[(size_t)(e4 & 0xffffu) * 16 + l];
        uint4 g5 = gb[(size_t)(e5 & 0xffffu) * 16 + l];
        uint4 g6 = gb[(size_t)(e6 & 0xffffu) * 16 + l];
        uint4 g7 = gb[(size_t)(e7 & 0xffffu) * 16 + l];
        ACCB(g0, e0) ACCB(g1, e1) ACCB(g2, e2) ACCB(g3, e3)
        ACCB(g4, e4) ACCB(g5, e5) ACCB(g6, e6) ACCB(g7, e7)
    }
    for (; p < c; ++p) {
        unsigned e = row[p];
        uint4 g = gb[(size_t)(e & 0xffffu) * 16 + l];
        ACCB(g, e)
    }
#undef ACCB
    if (SPLIT) {
        u16 h[8], lo[8];
        bsplit(a0, h[0], lo[0]); bsplit(a1, h[1], lo[1]);
        bsplit(a2, h[2], lo[2]); bsplit(a3, h[3], lo[3]);
        bsplit(a4, h[4], lo[4]); bsplit(a5, h[5], lo[5]);
        bsplit(a6, h[6], lo[6]); bsplit(a7, h[7], lo[7]);
        uint4 oh, ol;
        oh.x = (unsigned)h[0] | ((unsigned)h[1] << 16);
        oh.y = (unsigned)h[2] | ((unsigned)h[3] << 16);
        oh.z = (unsigned)h[4] | ((unsigned)h[5] << 16);
        oh.w = (unsigned)h[6] | ((unsigned)h[7] << 16);
        ol.x = (unsigned)lo[0] | ((unsigned)lo[1] << 16);
        ol.y = (unsigned)lo[2] | ((unsigned)lo[3] << 16);
        ol.z = (unsigned)lo[4] | ((unsigned)lo[5] << 16);
        ol.w = (unsigned)lo[6] | ((unsigned)lo[7] << 16);
        outh[(size_t)node * 16 + l] = oh;
        outl[(size_t)node * 16 + l] = ol;
    } else {
        outf[(size_t)node * 32 + l * 2]     = make_float4(a0, a1, a2, a3);
        outf[(size_t)node * 32 + l * 2 + 1] = make_float4(a4, a5, a6, a7);
    }
}

// ---------------- launch ----------------
extern "C" void kernel_launch(void* const* d_in, const int* in_sizes, int n_in,
                              void* d_out, int out_size, void* d_ws, size_t ws_size,
                              hipStream_t stream) {
    (void)n_in; (void)out_size; (void)ws_size;
    const float* x  = (const float*)d_in[0];
    const int*   ei = (const int*)d_in[1];
    const float* w  = (const float*)d_in[2];
    const float* W1 = (const float*)d_in[3];
    const float* b1 = (const float*)d_in[4];
    const float* W2 = (const float*)d_in[5];
    const float* b2 = (const float*)d_in[6];
    float* out = (float*)d_out;

    int N = in_sizes[0] / INCH;  // 50000
    int E = in_sizes[1] / 2;     // 800000
    const int* src = ei;
    const int* dst = ei + E;

    char* ws = (char*)d_ws;
    size_t off = 0;
    auto alloc = [&](size_t bytes) -> char* {
        size_t p = (off + 255) & ~(size_t)255;
        off = p + bytes;
        return ws + p;
    };
    u64*      packed = (u64*)     alloc((size_t)N * 8);
    float*    dinv   = (float*)   alloc((size_t)N * 4);
    unsigned* buck   = (unsigned*)alloc((size_t)N * CAP * 4);    // 12.8 MB
    unsigned* mask   = (unsigned*)alloc((size_t)N * NHID / 8);
    u16*      xb     = (u16*)     alloc((size_t)N * INCH * 2);   // bf16 x, later g2b
    u16*      axh    = (u16*)     alloc((size_t)N * INCH * 2);
    u16*      axl    = (u16*)     alloc((size_t)N * INCH * 2);
    u16*      hdh    = (u16*)     alloc((size_t)N * NHID * 2);
    u16*      hdl    = (u16*)     alloc((size_t)N * NHID * 2);
    u16*      w1h    = (u16*)     alloc((size_t)INCH * NHID * 2);
    u16*      w1l    = (u16*)     alloc((size_t)INCH * NHID * 2);
    u16*      w2h    = (u16*)     alloc((size_t)NHID * OUTCH * 2);
    u16*      w2l    = (u16*)     alloc((size_t)NHID * OUTCH * 2);
    // aliases (stream-ordered safe):
    u16*      g2b    = xb;               // xb dead after agg1
    float*    sp     = (float*)axh;      // axh+axl contiguous 25.6 MB, dead after gemm1

    int nb = (N + 255) / 256;
    int eb = (E + 255) / 256;
    int n8 = N * INCH / 8;
    int nwords = N * NHID / 32;
    int hb = (N + 7) / 8;     // k_norm: 8 nodes x 32 lanes
    int ab = (N + 15) / 16;   // aggregates: 16 nodes x 16 lanes

    k_zero64<<<nb, 256, 0, stream>>>(packed, N);
    k_fill64<<<eb, 256, 0, stream>>>(src, dst, w, packed, buck, E);
    k_dinv<<<nb, 256, 0, stream>>>(packed, dinv, N);
    k_norm<<<hb, 256, 0, stream>>>(buck, packed, dinv, N);
    k_prep<<<(n8 + 255) / 256, 256, 0, stream>>>((const float4*)x, (uint4*)xb, mask,
                                                 W1, w1h, w1l, W2, w2h, w2l, n8, nwords);

    // layer 1: ax = A@x (bf16 gather + fp32 self) -> split planes
    k_agg_b<true><<<ab, 256, 0, stream>>>((const uint4*)xb, (const float4*)x, dinv,
                                          packed, buck, (uint4*)axh, (uint4*)axl,
                                          nullptr, N);
    // hd = dropout(relu(ax @ W1 + b1)) -> split planes
    dim3 gg1(NHID / 128, (N + 63) / 64);
    gemm_mfma<64, 128, 0><<<gg1, 256, 0, stream>>>(axh, axl, w1h, w1l, b1, mask, nullptr,
                                                   hdh, hdl, nullptr, nullptr,
                                                   N, NHID, INCH);
    // g2 = hd @ W2 -> bf16 gather plane + fused self-part sp = dinv^2*g2 + b2
    dim3 gg2(OUTCH / 64, (N + 63) / 64);
    gemm_mfma<64, 64, 1><<<gg2, 256, 0, stream>>>(hdh, hdl, w2h, w2l, b2, nullptr, dinv,
                                                  nullptr, nullptr, g2b, sp,
                                                  N, OUTCH, NHID);
    // out = sp + sum val * g2b[col]
    k_agg_b<false><<<ab, 256, 0, stream>>>((const uint4*)g2b, (const float4*)sp, nullptr,
                                           packed, buck, nullptr, nullptr,
                                           (float4*)out, N);
}